// Round 7
// baseline (88.375 us; speedup 1.0000x reference)
//
#include <hip/hip_runtime.h>
#include <math.h>

// Weighted partial cross-entropy, MI355X — fused, chunk-rotated, 1-wave blocks.
// 2048 blocks x 64 threads; each block owns a 2048-pixel window processed as
// 4 chunks of 512 px, chunk order rotated by blockIdx&3. Single-wave blocks
// mean no idle waves at barriers; 8 blocks/CU x independent chunk phases keep
// scattered-gather requests and coalesced t/m streams mixed in the DRAM queue.
// Per chunk: ballot-compact labeled pixels into LDS (sorted), 19-plane gather
// + logsumexp, per-class {sum nll, count} in LDS; one flush; last block
// (done-flag) computes inverse-frequency weights + scalar loss.

constexpr int C      = 19;
constexpr int HWp    = 512 * 512;      // 2^18 pixels per image
constexpr int LOG2HW = 18;
constexpr int NPIX   = 16 * HWp;       // 4,194,304 = 2^22 (idx fits 22 bits)
constexpr int WPIX   = 2048;           // pixels per block window
constexpr int ABLK   = NPIX / WPIX;    // 2048 blocks (8 per CU, 1 wave each)
constexpr int CHUNK  = 512;            // pixels per chunk
constexpr int NCHUNK = WPIX / CHUNK;   // 4
constexpr int CITERS = CHUNK / 4 / 64; // 2 vec4 iters/lane/chunk

constexpr int OFF_DONE = 256;          // d_ws byte offset of done counter

__global__ __launch_bounds__(64) void wpce_fused(
        const float* __restrict__ pred,
        const int4* __restrict__ tgt4, const float4* __restrict__ msk4,
        char* __restrict__ wsb, float* __restrict__ out) {
    __shared__ unsigned ent[CHUNK];    // worst case: whole chunk labeled (2KB)
    __shared__ int sCnt, isLast;
    __shared__ float sS[C], sCt[C];
    const int tid = threadIdx.x;       // == lane (single wave)
    if (tid < C) { sS[tid] = 0.f; sCt[tid] = 0.f; }
    const unsigned long long lmask_lt = ((unsigned long long)1 << tid) - 1;
    const int rot = blockIdx.x & (NCHUNK - 1);

    for (int ck = 0; ck < NCHUNK; ++ck) {
        const int cs = (ck + rot) & (NCHUNK - 1);   // rotated chunk order
        if (tid == 0) sCnt = 0;
        __syncthreads();

        // ---- stream + ballot-compact this chunk (coalesced 16B loads) ----
        const int base_v = blockIdx.x * (WPIX / 4) + cs * (CHUNK / 4);
#pragma unroll
        for (int it = 0; it < CITERS; ++it) {
            const int v = base_v + it * 64 + tid;
            const int4   t = tgt4[v];
            const float4 m = msk4[v];
            const unsigned i0 = (unsigned)v * 4u;
            const float mm[4] = {m.x, m.y, m.z, m.w};
            const int   tt[4] = {t.x, t.y, t.z, t.w};
#pragma unroll
            for (int k = 0; k < 4; ++k) {
                const bool lab = (mm[k] != 0.f);
                const unsigned long long b = __ballot(lab);
                if (b) {
                    int base;
                    if (tid == 0) base = atomicAdd(&sCnt, __popcll(b));
                    base = __shfl(base, 0);
                    if (lab)       // ent[] holds a fully-labeled chunk: no cap
                        ent[base + __popcll(b & lmask_lt)] =
                            (i0 + k) | ((unsigned)tt[k] << 22);
                }
            }
        }
        __syncthreads();

        // ---- gather + logsumexp per labeled pixel of this chunk ----
        const int n = sCnt;
        for (int j = tid; j < n; j += 64) {
            const unsigned e = ent[j];
            const int idx = (int)(e & 0x3FFFFFu);
            const int t   = (int)(e >> 22);
            const float* p = pred + (((size_t)(idx >> LOG2HW) * C) << LOG2HW)
                                  + (idx & (HWp - 1));
            float x[C];
            float mx = -3.4e38f, xt = 0.f;
#pragma unroll
            for (int c = 0; c < C; ++c) {      // 19 independent strided loads
                const float v = p[(size_t)c << LOG2HW];
                x[c] = v;
                mx = fmaxf(mx, v);
                xt = (c == t) ? v : xt;        // static indices only (no scratch)
            }
            float se = 0.f;
#pragma unroll
            for (int c = 0; c < C; ++c) se += __expf(x[c] - mx);
            const float nll = mx + __logf(se) - xt;
            atomicAdd(&sS[t], nll);
            atomicAdd(&sCt[t], 1.f);           // mask is exactly 1.0 when labeled
        }
        __syncthreads();               // gathers done before next chunk's reset
    }

    // ---- flush per-class partials (device-scope atomics) ----
    float* ws = (float*)wsb;
    if (tid < C && (sS[tid] != 0.f || sCt[tid] != 0.f)) {
        atomicAdd(&ws[tid],     sS[tid]);
        atomicAdd(&ws[C + tid], sCt[tid]);
    }
    // __syncthreads lowers to s_waitcnt vmcnt(0)+s_barrier: flush performed
    // before the done-increment below.
    __syncthreads();
    if (tid == 0)
        isLast = (atomicAdd((int*)(wsb + OFF_DONE), 1) == (int)gridDim.x - 1);
    __syncthreads();

    // ---- last block finalizes: weights + scalar loss ----
    if (isLast) {
        const int l = tid;
        float S   = (l < C) ? __hip_atomic_load(&ws[l],     __ATOMIC_RELAXED,
                                  __HIP_MEMORY_SCOPE_AGENT) : 0.f;
        float cnt = (l < C) ? __hip_atomic_load(&ws[C + l], __ATOMIC_RELAXED,
                                  __HIP_MEMORY_SCOPE_AGENT) : 0.f;

        float total = cnt;
        for (int o = 1; o < 64; o <<= 1) total += __shfl_xor(total, o);

        float w = (l < C) ? total / (cnt + 1e-6f) : 0.f;   // inverse frequency
        float sw = w;
        for (int o = 1; o < 64; o <<= 1) sw += __shfl_xor(sw, o);

        float loss = (l < C) ? (w / sw * (float)C) * S : 0.f;
        for (int o = 1; o < 64; o <<= 1) loss += __shfl_xor(loss, o);

        if (l == 0) out[0] = (total > 0.f) ? loss / total : 0.f;
    }
}

extern "C" void kernel_launch(void* const* d_in, const int* in_sizes, int n_in,
                              void* d_out, int out_size, void* d_ws, size_t ws_size,
                              hipStream_t stream) {
    const float* pred = (const float*)d_in[0];
    const int*   tgt  = (const int*)  d_in[1];
    const float* msk  = (const float*)d_in[2];

    // zero {S[19], cnt[19]} accumulators + done flag (measured free: R2 vs R4)
    hipMemsetAsync(d_ws, 0, 512, stream);

    wpce_fused<<<ABLK, 64, 0, stream>>>(pred, (const int4*)tgt,
                                        (const float4*)msk,
                                        (char*)d_ws, (float*)d_out);
}

// Round 8
// 47.773 us; speedup vs baseline: 1.8499x; 1.8499x over previous
//
#include <hip/hip_runtime.h>
#include <math.h>

// Weighted partial cross-entropy, MI355X — fused, chunk-rotated pipeline.
// [BEST CONFIG — R6: 47.5µs. R7 falsified the concurrency lever (1-wave
// blocks: 88µs); R2/R4 falsified dispatch overhead (0µs); gather is pinned
// at ~45-48µs across 6x concurrency variation => HBM random-access wall
// (~1.2M touched 128B lines ~= 152MB at ~3.2 TB/s scattered service rate).]
// Each block owns an 8192-pixel window, processed as 4 chunks of 2048 px.
// Chunk order rotated by blockIdx&3: ~1/4 of blocks stream targets+mask
// (coalesced vec4) while ~3/4 do the scattered 19-plane gather, keeping
// stream traffic in the gather's DRAM slack. Per chunk: ballot-compact
// labeled pixels into LDS (sorted), gather+logsumexp, per-class
// {sum nll, count} in LDS; one device-atomic flush; last block (done-flag)
// computes inverse-frequency weights + scalar loss.

constexpr int C      = 19;
constexpr int HWp    = 512 * 512;      // 2^18 pixels per image
constexpr int LOG2HW = 18;
constexpr int NPIX   = 16 * HWp;       // 4,194,304 = 2^22 (idx fits 22 bits)
constexpr int WPIX   = 8192;           // pixels per block window
constexpr int ABLK   = NPIX / WPIX;    // 512 blocks
constexpr int CHUNK  = 2048;           // pixels per chunk
constexpr int NCHUNK = WPIX / CHUNK;   // 4
constexpr int CITERS = CHUNK / 4 / 256;// 2 vec4 iters/thread/chunk

constexpr int OFF_DONE = 256;          // d_ws byte offset of done counter

__global__ __launch_bounds__(256) void wpce_fused(
        const float* __restrict__ pred,
        const int4* __restrict__ tgt4, const float4* __restrict__ msk4,
        char* __restrict__ wsb, float* __restrict__ out) {
    __shared__ unsigned ent[CHUNK];    // worst-case whole chunk labeled (8KB)
    __shared__ int sCnt, isLast;
    __shared__ float sS[C], sCt[C];
    const int tid  = threadIdx.x;
    const int lane = tid & 63;
    if (tid < C) { sS[tid] = 0.f; sCt[tid] = 0.f; }
    const unsigned long long lmask_lt = ((unsigned long long)1 << lane) - 1;
    const int rot = blockIdx.x & (NCHUNK - 1);

    for (int ck = 0; ck < NCHUNK; ++ck) {
        const int cs = (ck + rot) & (NCHUNK - 1);   // rotated chunk order
        if (tid == 0) sCnt = 0;
        __syncthreads();               // reset visible (prev gather done: loop-end barrier)

        // ---- stream + ballot-compact this chunk (coalesced 16B loads) ----
        const int base_v = blockIdx.x * (WPIX / 4) + cs * (CHUNK / 4);
#pragma unroll
        for (int it = 0; it < CITERS; ++it) {
            const int v = base_v + it * 256 + tid;
            const int4   t = tgt4[v];
            const float4 m = msk4[v];
            const unsigned i0 = (unsigned)v * 4u;
            const float mm[4] = {m.x, m.y, m.z, m.w};
            const int   tt[4] = {t.x, t.y, t.z, t.w};
#pragma unroll
            for (int k = 0; k < 4; ++k) {
                const bool lab = (mm[k] != 0.f);
                const unsigned long long b = __ballot(lab);
                if (b) {
                    int base;
                    if (lane == 0) base = atomicAdd(&sCnt, __popcll(b));
                    base = __shfl(base, 0);
                    if (lab)       // ent[] can hold a fully-labeled chunk: no cap
                        ent[base + __popcll(b & lmask_lt)] =
                            (i0 + k) | ((unsigned)tt[k] << 22);
                }
            }
        }
        __syncthreads();

        // ---- gather + logsumexp per labeled pixel of this chunk ----
        const int n = sCnt;
        for (int j = tid; j < n; j += 256) {
            const unsigned e = ent[j];
            const int idx = (int)(e & 0x3FFFFFu);
            const int t   = (int)(e >> 22);
            const float* p = pred + (((size_t)(idx >> LOG2HW) * C) << LOG2HW)
                                  + (idx & (HWp - 1));
            float x[C];
            float mx = -3.4e38f, xt = 0.f;
#pragma unroll
            for (int c = 0; c < C; ++c) {      // 19 independent strided loads
                const float v = p[(size_t)c << LOG2HW];
                x[c] = v;
                mx = fmaxf(mx, v);
                xt = (c == t) ? v : xt;        // static indices only (no scratch)
            }
            float se = 0.f;
#pragma unroll
            for (int c = 0; c < C; ++c) se += __expf(x[c] - mx);
            const float nll = mx + __logf(se) - xt;
            atomicAdd(&sS[t], nll);
            atomicAdd(&sCt[t], 1.f);           // mask is exactly 1.0 when labeled
        }
        __syncthreads();               // gathers done before next chunk's reset
    }

    // ---- flush per-class partials (device-scope atomics) ----
    float* ws = (float*)wsb;
    if (tid < C && (sS[tid] != 0.f || sCt[tid] != 0.f)) {
        atomicAdd(&ws[tid],     sS[tid]);
        atomicAdd(&ws[C + tid], sCt[tid]);
    }
    // __syncthreads lowers to s_waitcnt vmcnt(0)+s_barrier: flush performed
    // before the done-increment below.
    __syncthreads();
    if (tid == 0)
        isLast = (atomicAdd((int*)(wsb + OFF_DONE), 1) == ABLK - 1);
    __syncthreads();

    // ---- last block finalizes: weights + scalar loss ----
    if (isLast && tid < 64) {
        const int l = tid;
        float S   = (l < C) ? __hip_atomic_load(&ws[l],     __ATOMIC_RELAXED,
                                  __HIP_MEMORY_SCOPE_AGENT) : 0.f;
        float cnt = (l < C) ? __hip_atomic_load(&ws[C + l], __ATOMIC_RELAXED,
                                  __HIP_MEMORY_SCOPE_AGENT) : 0.f;

        float total = cnt;
        for (int o = 1; o < 64; o <<= 1) total += __shfl_xor(total, o);

        float w = (l < C) ? total / (cnt + 1e-6f) : 0.f;   // inverse frequency
        float sw = w;
        for (int o = 1; o < 64; o <<= 1) sw += __shfl_xor(sw, o);

        float loss = (l < C) ? (w / sw * (float)C) * S : 0.f;
        for (int o = 1; o < 64; o <<= 1) loss += __shfl_xor(loss, o);

        if (l == 0) out[0] = (total > 0.f) ? loss / total : 0.f;
    }
}

extern "C" void kernel_launch(void* const* d_in, const int* in_sizes, int n_in,
                              void* d_out, int out_size, void* d_ws, size_t ws_size,
                              hipStream_t stream) {
    const float* pred = (const float*)d_in[0];
    const int*   tgt  = (const int*)  d_in[1];
    const float* msk  = (const float*)d_in[2];

    // zero {S[19], cnt[19]} accumulators + done flag (measured free: R2 vs R4)
    hipMemsetAsync(d_ws, 0, 512, stream);

    wpce_fused<<<ABLK, 256, 0, stream>>>(pred, (const int4*)tgt,
                                         (const float4*)msk,
                                         (char*)d_ws, (float*)d_out);
}